// Round 2
// baseline (690.158 us; speedup 1.0000x reference)
//
#include <hip/hip_runtime.h>
#include <hip/hip_bf16.h>

#define H_FEATS 128
#define HIDDEN  32

// One thread per edge. hidden[32] lives in VGPRs (all j-loops fully
// unrolled -> static indexing, no scratch). W1/b1/W2/b2 are wave-uniform so
// the compiler turns them into scalar (s_load) accesses; v_fmac_f32 can take
// one SGPR operand, so the inner loop is pure FMA on the VALU.
__global__ __launch_bounds__(256) void edge_mlp_kernel(
    const float* __restrict__ h,
    const int*   __restrict__ src,
    const int*   __restrict__ dst,
    const float* __restrict__ W1,   // [128][32] row-major
    const float* __restrict__ b1,   // [32]
    const float* __restrict__ W2,   // [32]
    const float* __restrict__ b2,   // [1]
    float*       __restrict__ out,  // [E]
    int n_edges)
{
    int e = blockIdx.x * blockDim.x + threadIdx.x;
    if (e >= n_edges) return;

    const float* hs = h + (size_t)src[e] * H_FEATS;
    const float* hd = h + (size_t)dst[e] * H_FEATS;

    float hidden[HIDDEN];
#pragma unroll
    for (int j = 0; j < HIDDEN; ++j) hidden[j] = b1[j];

    // 128 features in chunks of 4 (float4 loads). Partial unroll keeps code
    // size sane while the fully-unrolled j-loop keeps hidden[] in registers.
#pragma unroll 4
    for (int f0 = 0; f0 < H_FEATS; f0 += 4) {
        float4 a = *reinterpret_cast<const float4*>(hs + f0);
        float4 b = *reinterpret_cast<const float4*>(hd + f0);
        float he0 = a.x * b.x;
        float he1 = a.y * b.y;
        float he2 = a.z * b.z;
        float he3 = a.w * b.w;
        const float* w0 = W1 + (size_t)(f0 + 0) * HIDDEN;
        const float* w1 = W1 + (size_t)(f0 + 1) * HIDDEN;
        const float* w2 = W1 + (size_t)(f0 + 2) * HIDDEN;
        const float* w3 = W1 + (size_t)(f0 + 3) * HIDDEN;
#pragma unroll
        for (int j = 0; j < HIDDEN; ++j) {
            float acc = hidden[j];
            acc = fmaf(he0, w0[j], acc);
            acc = fmaf(he1, w1[j], acc);
            acc = fmaf(he2, w2[j], acc);
            acc = fmaf(he3, w3[j], acc);
            hidden[j] = acc;
        }
    }

    float score = b2[0];
#pragma unroll
    for (int j = 0; j < HIDDEN; ++j) {
        float r = hidden[j] > 0.0f ? hidden[j] : 0.0f;
        score = fmaf(r, W2[j], score);
    }
    out[e] = score;
}

extern "C" void kernel_launch(void* const* d_in, const int* in_sizes, int n_in,
                              void* d_out, int out_size, void* d_ws, size_t ws_size,
                              hipStream_t stream) {
    const float* h   = (const float*)d_in[0];
    const int*   src = (const int*)  d_in[1];
    const int*   dst = (const int*)  d_in[2];
    const float* W1  = (const float*)d_in[3];
    const float* b1  = (const float*)d_in[4];
    const float* W2  = (const float*)d_in[5];
    const float* b2  = (const float*)d_in[6];
    float* out = (float*)d_out;

    int n_edges = in_sizes[1];
    int block = 256;
    int grid = (n_edges + block - 1) / block;
    edge_mlp_kernel<<<grid, block, 0, stream>>>(h, src, dst, W1, b1, W2, b2,
                                                out, n_edges);
}

// Round 3
// 292.559 us; speedup vs baseline: 2.3590x; 2.3590x over previous
//
#include <hip/hip_runtime.h>
#include <hip/hip_bf16.h>
#include <hip/hip_fp16.h>

#define H_FEATS 128
#define HIDDEN  32

union H8 { uint4 u; __half2 h2[4]; };

// Pass 1: convert h (fp32, [N,128]) to fp16 rows in d_ws. 8 floats/thread.
__global__ __launch_bounds__(256) void convert_h_kernel(
    const float* __restrict__ h, __half* __restrict__ hh, int n8)
{
    int i = blockIdx.x * blockDim.x + threadIdx.x;
    if (i >= n8) return;
    const float4* s = reinterpret_cast<const float4*>(h) + (size_t)i * 2;
    float4 a = s[0], b = s[1];
    H8 r;
    r.h2[0] = __floats2half2_rn(a.x, a.y);
    r.h2[1] = __floats2half2_rn(a.z, a.w);
    r.h2[2] = __floats2half2_rn(b.x, b.y);
    r.h2[3] = __floats2half2_rn(b.z, b.w);
    reinterpret_cast<uint4*>(hh)[i] = r.u;
}

// Pass 2: one thread per edge, gather two 256B fp16 rows, fp32 MLP.
__global__ __launch_bounds__(256) void edge_mlp_fp16_kernel(
    const __half* __restrict__ hh,
    const int*   __restrict__ src,
    const int*   __restrict__ dst,
    const float* __restrict__ W1,   // [128][32] row-major
    const float* __restrict__ b1,   // [32]
    const float* __restrict__ W2,   // [32]
    const float* __restrict__ b2,   // [1]
    float*       __restrict__ out,  // [E]
    int n_edges)
{
    int e = blockIdx.x * blockDim.x + threadIdx.x;
    if (e >= n_edges) return;

    const __half* hs = hh + (size_t)src[e] * H_FEATS;
    const __half* hd = hh + (size_t)dst[e] * H_FEATS;

    float hidden[HIDDEN];
#pragma unroll
    for (int j = 0; j < HIDDEN; ++j) hidden[j] = b1[j];

    // 128 features in chunks of 8 (one uint4 = 8 fp16 per row per chunk).
#pragma unroll 2
    for (int f0 = 0; f0 < H_FEATS; f0 += 8) {
        H8 A, B;
        A.u = *reinterpret_cast<const uint4*>(hs + f0);
        B.u = *reinterpret_cast<const uint4*>(hd + f0);
        float he[8];
#pragma unroll
        for (int k = 0; k < 4; ++k) {
            float2 a = __half22float2(A.h2[k]);
            float2 b = __half22float2(B.h2[k]);
            he[2 * k]     = a.x * b.x;
            he[2 * k + 1] = a.y * b.y;
        }
        const float* w = W1 + (size_t)f0 * HIDDEN;
#pragma unroll
        for (int j = 0; j < HIDDEN; ++j) {
            float acc = hidden[j];
#pragma unroll
            for (int k = 0; k < 8; ++k)
                acc = fmaf(he[k], w[(size_t)k * HIDDEN + j], acc);
            hidden[j] = acc;
        }
    }

    float score = b2[0];
#pragma unroll
    for (int j = 0; j < HIDDEN; ++j) {
        float r = hidden[j] > 0.0f ? hidden[j] : 0.0f;
        score = fmaf(r, W2[j], score);
    }
    out[e] = score;
}

// Fallback (ws too small): original fp32 gather kernel.
__global__ __launch_bounds__(256) void edge_mlp_kernel(
    const float* __restrict__ h,
    const int*   __restrict__ src,
    const int*   __restrict__ dst,
    const float* __restrict__ W1,
    const float* __restrict__ b1,
    const float* __restrict__ W2,
    const float* __restrict__ b2,
    float*       __restrict__ out,
    int n_edges)
{
    int e = blockIdx.x * blockDim.x + threadIdx.x;
    if (e >= n_edges) return;

    const float* hs = h + (size_t)src[e] * H_FEATS;
    const float* hd = h + (size_t)dst[e] * H_FEATS;

    float hidden[HIDDEN];
#pragma unroll
    for (int j = 0; j < HIDDEN; ++j) hidden[j] = b1[j];

#pragma unroll 4
    for (int f0 = 0; f0 < H_FEATS; f0 += 4) {
        float4 a = *reinterpret_cast<const float4*>(hs + f0);
        float4 b = *reinterpret_cast<const float4*>(hd + f0);
        float he0 = a.x * b.x, he1 = a.y * b.y, he2 = a.z * b.z, he3 = a.w * b.w;
        const float* w0 = W1 + (size_t)(f0 + 0) * HIDDEN;
        const float* w1 = W1 + (size_t)(f0 + 1) * HIDDEN;
        const float* w2 = W1 + (size_t)(f0 + 2) * HIDDEN;
        const float* w3 = W1 + (size_t)(f0 + 3) * HIDDEN;
#pragma unroll
        for (int j = 0; j < HIDDEN; ++j) {
            float acc = hidden[j];
            acc = fmaf(he0, w0[j], acc);
            acc = fmaf(he1, w1[j], acc);
            acc = fmaf(he2, w2[j], acc);
            acc = fmaf(he3, w3[j], acc);
            hidden[j] = acc;
        }
    }

    float score = b2[0];
#pragma unroll
    for (int j = 0; j < HIDDEN; ++j) {
        float r = hidden[j] > 0.0f ? hidden[j] : 0.0f;
        score = fmaf(r, W2[j], score);
    }
    out[e] = score;
}

extern "C" void kernel_launch(void* const* d_in, const int* in_sizes, int n_in,
                              void* d_out, int out_size, void* d_ws, size_t ws_size,
                              hipStream_t stream) {
    const float* h   = (const float*)d_in[0];
    const int*   src = (const int*)  d_in[1];
    const int*   dst = (const int*)  d_in[2];
    const float* W1  = (const float*)d_in[3];
    const float* b1  = (const float*)d_in[4];
    const float* W2  = (const float*)d_in[5];
    const float* b2  = (const float*)d_in[6];
    float* out = (float*)d_out;

    int n_nodes_feats = in_sizes[0];          // N * 128
    int n_edges = in_sizes[1];
    size_t need = (size_t)n_nodes_feats * sizeof(__half);

    int block = 256;
    int grid = (n_edges + block - 1) / block;

    if (ws_size >= need) {
        __half* hh = (__half*)d_ws;
        int n8 = n_nodes_feats / 8;
        convert_h_kernel<<<(n8 + block - 1) / block, block, 0, stream>>>(h, hh, n8);
        edge_mlp_fp16_kernel<<<grid, block, 0, stream>>>(hh, src, dst, W1, b1, W2, b2,
                                                         out, n_edges);
    } else {
        edge_mlp_kernel<<<grid, block, 0, stream>>>(h, src, dst, W1, b1, W2, b2,
                                                    out, n_edges);
    }
}